// Round 12
// baseline (863.853 us; speedup 1.0000x reference)
//
#include <hip/hip_runtime.h>
#include <cstdint>
#include <cstddef>
#include <climits>

// DacResidualVectorQuantize on MI355X. Exact-class (f64-internal, f32
// materialization) chain + cluster-argmin — green since R7 (indices exact).
// R12: fix VGPR spill (launch_bounds(512,2) => 128-VGPR cap; R11's (512,4)
// capped at 64 and spilled rr[64] -> 290MB scratch traffic). LDS layout:
// 16B-chunk XOR swizzle (chunk q of row r at slot q^((r>>2)&1)) -> 2x
// ds_read_b128 per row (was 4x b64), swap bit lane-constant for all hot
// access patterns, 2-way bank aliasing (free).

#define NCOL 32768
#define QBASE 33554432ull  // 16*1024*2048
#define PREF32 2e-5f       // f32 prefilter band (score units)
#define TOLS 1.25e-7       // score tolerance (= dist tol 2.5e-7 / 2)
#define NEGINF (-__builtin_inff())

// f32 round of exact sum of 8 f32 values
__device__ __forceinline__ float s8_exact(const float* x) {
  double a = 0.0;
#pragma unroll
  for (int k = 0; k < 8; ++k) a += (double)x[k];
  return (float)a;
}

// -------------------------------------------------------------- K1: prep
__global__ __launch_bounds__(256) void k_prep(
    const float* __restrict__ in_v, const float* __restrict__ in_g,
    const float* __restrict__ out_v, const float* __restrict__ out_g,
    const float* __restrict__ cbk, float* __restrict__ w_inT,
    float* __restrict__ w_outT, float* __restrict__ cnf,
    float* __restrict__ cn2h, double* __restrict__ loss_acc) {
#pragma clang fp contract(off)
  __shared__ double red[256];
  int bid = blockIdx.x, tid = threadIdx.x;
  if (bid == 0 && tid == 0) loss_acc[0] = 0.0;
  if (bid < 72) {
    int i = bid >> 3, o = bid & 7;
    const float* v = in_v + (size_t)bid * 1024;
    double p = 0.0;
    for (int d = tid; d < 1024; d += 256) {
      float sqv = v[d] * v[d];  // integer_pow eqn f32
      p += (double)sqv;         // exact accumulation
    }
    red[tid] = p;
    __syncthreads();
    for (int s = 128; s > 0; s >>= 1) {
      if (tid < s) red[tid] += red[tid + s];
      __syncthreads();
    }
    float n2f = (float)red[0];             // reduce_sum -> f32 aval
    float nrm = (float)sqrt((double)n2f);  // correctly-rounded f32 sqrt
    float g = in_g[bid];
    for (int d = tid; d < 1024; d += 256) {
      float gv = g * v[d];  // mul eqn f32
      float w = gv / nrm;   // div eqn f32
      w_inT[((size_t)i * 1024 + d) * 8 + o] = w;
    }
  } else {
    int id = (bid - 72) * 256 + tid;
    if (id < 9216) {
      int r = id;  // (i,d) row of out_v [9][1024][8]
      const float* v = out_v + (size_t)r * 8;
      float sq[8];
#pragma unroll
      for (int k = 0; k < 8; ++k) sq[k] = v[k] * v[k];
      float n2f = s8_exact(sq);
      float nrm = (float)sqrt((double)n2f);
      float g = out_g[r];
#pragma unroll
      for (int k = 0; k < 8; ++k) {
        float gv = g * v[k];
        w_outT[(size_t)r * 8 + k] = gv / nrm;
      }
    } else if (id < 18432) {
      int r = id - 9216;  // code row (i*1024+c)
      const float* v = cbk + (size_t)r * 8;
      float sq[8];
#pragma unroll
      for (int k = 0; k < 8; ++k) sq[k] = v[k] * v[k];
      float n2f = s8_exact(sq);
      float nrm = (float)sqrt((double)n2f);
      float den = fmaxf(nrm, 1e-12f);
      float cn[8], c2[8];
#pragma unroll
      for (int k = 0; k < 8; ++k) {
        cn[k] = v[k] / den;
        cnf[(size_t)r * 8 + k] = cn[k];
        c2[k] = cn[k] * cn[k];
      }
      cn2h[r] = 0.5f * s8_exact(c2);  // exact halving (for f32 prefilter)
    }
  }
}

// ------------------------------------------------ K2: fused 9-stage VQ
// 512 thr = 32 columns x 16 lanes; rr[64] f32 regs = resid slice (d=l+16j).
// LDS: tabs[16384] = two swizzled 8192-float tables (roles alternate; also
// aliased as 64x36 hst tile), smal[1024] (0.5*cn2 or bias).
__global__ __launch_bounds__(512, 2) void k_fused(
    const float* __restrict__ h, const float* __restrict__ w_inT,
    const float* __restrict__ w_outT, const float* __restrict__ in_b,
    const float* __restrict__ out_b, const float* __restrict__ cnf,
    const float* __restrict__ cn2h, const float* __restrict__ cbk, int nq,
    float* __restrict__ out, double* __restrict__ loss_acc) {
#pragma clang fp contract(off)
  __shared__ __align__(16) float tabs[16384];
  __shared__ float smal[1024];
  __shared__ double lred[32];

  int tid = threadIdx.x;
  int g = tid >> 4;  // column group 0..31
  int l = tid & 15;  // lane in group
  int b = blockIdx.x >> 6;
  int t0 = (blockIdx.x & 63) * 32;
  int t = t0 + g;
  int sw = (l >> 2) & 1;      // lane-constant chunk-swap bit
  int oLo = sw * 4;           // offset of logical chunk0
  int oHi = 4 - sw * 4;       // offset of logical chunk1

  // swizzled staging: row r (8 floats), 16B chunk q -> slot q^((r>>2)&1)
  auto stage_tab = [&](float* dst, const float* src) {
    for (int u = tid; u < 2048; u += 512) {
      int r = u >> 1, q = u & 1;
      float4 v = *(const float4*)&src[(size_t)r * 8 + q * 4];
      int qq = q ^ ((r >> 2) & 1);
      *(float4*)&dst[r * 8 + qq * 4] = v;
    }
  };

  // ---- load resid = h into registers (coalesced via hst tile = tabs alias)
  float rr[64];
  {
    float* hst = tabs;  // [64][36]
#pragma unroll
    for (int cc = 0; cc < 16; ++cc) {
      __syncthreads();
      int row = tid >> 3, c4 = (tid & 7) * 4;
      *(float4*)&hst[row * 36 + c4] =
          *(const float4*)&h[((size_t)b * 1024 + cc * 64 + row) * 2048 + t0 + c4];
      __syncthreads();
#pragma unroll
      for (int jj = 0; jj < 4; ++jj)
        rr[cc * 4 + jj] = hst[(l + 16 * jj) * 36 + g];
    }
  }
  __syncthreads();

  float* fb = tabs;         // fold buffer (w_in[i])
  float* ob = tabs + 8192;  // other buffer (cn[i] / next w_in)
  stage_tab(fb, w_inT);     // w_in[0]
  __syncthreads();

  double lsum = 0.0;
  size_t idx_base = QBASE;
  size_t lat_base = QBASE + (size_t)16 * nq * 2048;

  for (int i = 0; i < nq; ++i) {
    // ---- fold: z_e = w_in[i] . resid (f64 exact-class)
    double za[8] = {0, 0, 0, 0, 0, 0, 0, 0};
    {
      const float* rp = fb + l * 8;
#pragma unroll
      for (int j = 0; j < 64; ++j) {
        float4 wl = *(const float4*)&rp[oLo];
        float4 wh = *(const float4*)&rp[oHi];
        double rv = (double)rr[j];
        za[0] = fma((double)wl.x, rv, za[0]);
        za[1] = fma((double)wl.y, rv, za[1]);
        za[2] = fma((double)wl.z, rv, za[2]);
        za[3] = fma((double)wl.w, rv, za[3]);
        za[4] = fma((double)wh.x, rv, za[4]);
        za[5] = fma((double)wh.y, rv, za[5]);
        za[6] = fma((double)wh.z, rv, za[6]);
        za[7] = fma((double)wh.w, rv, za[7]);
        rp += 128;
      }
    }
#pragma unroll
    for (int o = 0; o < 8; ++o) {
#pragma unroll
      for (int m = 1; m < 16; m <<= 1) za[o] += __shfl_xor(za[o], m, 64);
    }
    float z[8];
#pragma unroll
    for (int o = 0; o < 8; ++o)
      z[o] = (float)za[o] + in_b[i * 8 + o];  // add eqn f32
    __syncthreads();  // fb free (fold done)

    // ---- load cn[i] into ob, 0.5*cn2 into smal
    stage_tab(ob, cnf + (size_t)i * 8192);
    for (int u = tid; u < 1024; u += 512) smal[u] = cn2h[i * 1024 + u];
    __syncthreads();

    // ---- en (f32, exact-class)
    float sq[8];
#pragma unroll
    for (int k = 0; k < 8; ++k) sq[k] = z[k] * z[k];
    float n2f = s8_exact(sq);
    float nrm = (float)sqrt((double)n2f);
    float den = fmaxf(nrm, 1e-12f);
    float en[8];
#pragma unroll
    for (int k = 0; k < 8; ++k) en[k] = z[k] / den;

    // ---- f32 scan, 64 interleaved codes/lane, top-2 cache
    float s0 = NEGINF, s1 = NEGINF;
    int i0 = 0, i1 = 0;
    {
      const float* rp = ob + l * 8;
      int code = l;
      for (int c = 0; c < 64; ++c) {
        float4 A = *(const float4*)&rp[oLo];
        float4 B = *(const float4*)&rp[oHi];
        float s = fmaf(en[0], A.x, -smal[code]);
        s = fmaf(en[1], A.y, s);
        s = fmaf(en[2], A.z, s);
        s = fmaf(en[3], A.w, s);
        s = fmaf(en[4], B.x, s);
        s = fmaf(en[5], B.y, s);
        s = fmaf(en[6], B.z, s);
        s = fmaf(en[7], B.w, s);
        if (s > s1) {
          if (s > s0) {
            s1 = s0; i1 = i0; s0 = s; i0 = code;
          } else {
            s1 = s; i1 = code;
          }
        }
        rp += 128;
        code += 16;
      }
    }
    // global f32 max -> prefilter cut
    float g32 = s0;
#pragma unroll
    for (int m = 1; m < 16; m <<= 1) g32 = fmaxf(g32, __shfl_xor(g32, m, 64));
    float cut32 = g32 - PREF32;
    // f64 rescore of qualifying cached codes
    double cs[2];
    int cidx[2] = {i0, i1};
    float sf[2] = {s0, s1};
    double b64 = -1e300;
#pragma unroll
    for (int u = 0; u < 2; ++u) {
      cs[u] = -1e300;
      if (sf[u] >= cut32) {
        int r = cidx[u];
        int swr = (r >> 2) & 1;
        const float* rp = ob + r * 8;
        float4 A = *(const float4*)&rp[swr * 4];
        float4 B = *(const float4*)&rp[4 - swr * 4];
        float cv[8] = {A.x, A.y, A.z, A.w, B.x, B.y, B.z, B.w};
        double a = 0.0, q = 0.0;
#pragma unroll
        for (int k = 0; k < 8; ++k) {
          double cd = (double)cv[k];
          a = fma((double)en[k], cd, a);
          q = fma(cd, cd, q);
        }
        cs[u] = a - 0.5 * q;
        if (cs[u] > b64) b64 = cs[u];
      }
    }
#pragma unroll
    for (int m = 1; m < 16; m <<= 1) b64 = fmax(b64, __shfl_xor(b64, m, 64));
    double cut64 = b64 - TOLS;
    int loc = INT_MAX;
#pragma unroll
    for (int u = 0; u < 2; ++u)
      if (cs[u] >= cut64 && cidx[u] < loc) loc = cidx[u];
#pragma unroll
    for (int m = 1; m < 16; m <<= 1) loc = min(loc, __shfl_xor(loc, m, 64));
    __syncthreads();  // ob free (scan done)

    // ---- load w_out[i] -> fb, bias -> smal, w_in[i+1] -> ob
    stage_tab(fb, w_outT + (size_t)i * 8192);
    for (int u = tid; u < 1024; u += 512) smal[u] = out_b[i * 1024 + u];
    if (i + 1 < nq) stage_tab(ob, w_inT + (size_t)(i + 1) * 8192);
    __syncthreads();

    // ---- zq_st + outputs + loss
    const float* zp = &cbk[((size_t)i * 1024 + loc) * 8];
    float st[8];
#pragma unroll
    for (int k = 0; k < 8; ++k) {
      float zq = zp[k];
      float dlt = zq - z[k];  // sub eqn f32
      st[k] = z[k] + dlt;     // add eqn f32 (straight-through)
    }
    if (l == 0) {
#pragma unroll
      for (int k = 0; k < 8; ++k) {
        float df = z[k] - zp[k];
        lsum += (double)df * (double)df;
      }
      out[idx_base + ((size_t)b * nq + i) * 2048 + t] = (float)loc;
#pragma unroll
      for (int o = 0; o < 8; ++o)
        out[lat_base + ((size_t)b * (nq * 8) + (i * 8 + o)) * 2048 + t] = z[o];
    }

    // ---- update: resid -= f32(f64 dot8(w_out[d], st)) + bias (in-register)
    {
      const float* rp = fb + l * 8;
      int d = l;
#pragma unroll
      for (int j = 0; j < 64; ++j) {
        float4 wl = *(const float4*)&rp[oLo];
        float4 wh = *(const float4*)&rp[oHi];
        double a = fma((double)wl.x, (double)st[0], 0.0);
        a = fma((double)wl.y, (double)st[1], a);
        a = fma((double)wl.z, (double)st[2], a);
        a = fma((double)wl.w, (double)st[3], a);
        a = fma((double)wh.x, (double)st[4], a);
        a = fma((double)wh.y, (double)st[5], a);
        a = fma((double)wh.z, (double)st[6], a);
        a = fma((double)wh.w, (double)st[7], a);
        float q = (float)a + smal[d];  // add eqn f32
        rr[j] = rr[j] - q;             // sub eqn f32
        rp += 128;
        d += 16;
      }
    }
    // swap roles: ob holds w_in[i+1] -> next fold buffer
    float* tmp = fb; fb = ob; ob = tmp;
  }

  // ---- quant = h - resid_final (coalesced via hst tile = tabs alias)
  {
    float* hst = tabs;
#pragma unroll
    for (int cc = 0; cc < 16; ++cc) {
      __syncthreads();
#pragma unroll
      for (int jj = 0; jj < 4; ++jj)
        hst[(l + 16 * jj) * 36 + g] = rr[cc * 4 + jj];
      __syncthreads();
      int row = tid >> 3, c4 = (tid & 7) * 4;
      size_t adr = ((size_t)b * 1024 + cc * 64 + row) * 2048 + t0 + c4;
      float4 hv = *(const float4*)&h[adr];
      float4 rv = *(float4*)&hst[row * 36 + c4];
      float4 qv = {hv.x - rv.x, hv.y - rv.y, hv.z - rv.z, hv.w - rv.w};
      *(float4*)&out[adr] = qv;
    }
  }

  // ---- loss reduce (one atomic per block)
  if (l == 0) lred[g] = lsum;
  __syncthreads();
  if (tid == 0) {
    double s = 0.0;
    for (int u = 0; u < 32; ++u) s += lred[u];
    atomicAdd(loss_acc, s);
  }
}

// --------------------------------------------------------- K3: losses
__global__ void k_fin(const double* __restrict__ loss_acc, int nq,
                      float* __restrict__ out) {
  if (threadIdx.x == 0 && blockIdx.x == 0) {
    float v = (float)(loss_acc[0] / 262144.0);  // B*CD*T
    size_t base = QBASE + (size_t)16 * nq * 2048 + (size_t)16 * nq * 8 * 2048;
    out[base] = v;
    out[base + 1] = v;
  }
}

// ------------------------------------------------------------------ launch
extern "C" void kernel_launch(void* const* d_in, const int* in_sizes, int n_in,
                              void* d_out, int out_size, void* d_ws,
                              size_t ws_size, hipStream_t stream) {
  (void)in_sizes; (void)n_in; (void)ws_size;
  const float* h     = (const float*)d_in[0];
  const float* in_v  = (const float*)d_in[1];
  const float* in_g  = (const float*)d_in[2];
  const float* in_b  = (const float*)d_in[3];
  const float* out_v = (const float*)d_in[4];
  const float* out_g = (const float*)d_in[5];
  const float* out_b = (const float*)d_in[6];
  const float* cbk   = (const float*)d_in[7];
  float* out = (float*)d_out;
  char* ws = (char*)d_ws;

  long long nq_ll = ((long long)out_size - (long long)QBASE - 2) / 294912LL;
  int nq = (int)nq_ll;
  if (nq < 1) nq = 1;
  if (nq > 9) nq = 9;

  size_t off = 0;
  auto alloc = [&](size_t bytes) {
    size_t o = off;
    off += (bytes + 255) & ~(size_t)255;
    return o;
  };
  float*  w_inT  = (float*)(ws + alloc((size_t)9 * 1024 * 8 * 4));
  float*  w_outT = (float*)(ws + alloc((size_t)9 * 1024 * 8 * 4));
  float*  cnf    = (float*)(ws + alloc((size_t)9 * 1024 * 8 * 4));
  float*  cn2h   = (float*)(ws + alloc((size_t)9 * 1024 * 4));
  double* lossa  = (double*)(ws + alloc(256));

  k_prep<<<dim3(144), 256, 0, stream>>>(in_v, in_g, out_v, out_g, cbk, w_inT,
                                        w_outT, cnf, cn2h, lossa);
  k_fused<<<dim3(1024), 512, 0, stream>>>(h, w_inT, w_outT, in_b, out_b, cnf,
                                          cn2h, cbk, nq, out, lossa);
  k_fin<<<1, 64, 0, stream>>>(lossa, nq, out);
}